// Round 1
// baseline (5677.172 us; speedup 1.0000x reference)
//
#include <hip/hip_runtime.h>
#include <math.h>

// Problem constants (fixed by reference): Nq=20000, K=32, Cin=3, Fc=64, Co=64
#define KNB 32
#define FC 64
#define CIN 3
#define CO 64

__global__ __launch_bounds__(256, 4) void GCT_61272003445298_kernel(
    const float* __restrict__ q_points,   // [Nq,3]
    const float* __restrict__ s_points,   // [Nq,3]
    const int*   __restrict__ neighb,     // [Nq,32]
    const float* __restrict__ feat,       // [Nq,64]
    const float* __restrict__ W_pos2,     // [64,3]
    const float* __restrict__ W_attn,     // [192,64]
    const float* __restrict__ W_res,      // [64,64]
    const float* __restrict__ bnq_g, const float* __restrict__ bnq_b,
    const float* __restrict__ bnq_m, const float* __restrict__ bnq_v,
    const float* __restrict__ bnp_g, const float* __restrict__ bnp_b,
    const float* __restrict__ bnp_m, const float* __restrict__ bnp_v,
    const float* __restrict__ bn1_g, const float* __restrict__ bn1_b,
    const float* __restrict__ bn1_m, const float* __restrict__ bn1_v,
    const float* __restrict__ bnr_g, const float* __restrict__ bnr_b,
    const float* __restrict__ bnr_m, const float* __restrict__ bnr_v,
    float* __restrict__ out, int Nq)
{
    const int n = blockIdx.x;
    const int t = threadIdx.x;
    if (n >= Nq) return;

    const float EPS = 1e-5f;

    __shared__ float sXq[FC];          // lrelu(bnq(feat[n]))
    __shared__ float sPos0[CIN];       // lrelu(bnp(s_points[n]))
    __shared__ float sXv[KNB][4];      // x_v[k][i]
    __shared__ int   sIdx[KNB];
    __shared__ float sWp[FC*CIN];      // W_pos2 staged
    __shared__ float sBn1s[CO], sBn1b[CO], sBnrs[CO], sBnrb[CO];
    __shared__ float sAttn[KNB][68];   // attn_pre -> attn (pitch 68: bank spread)
    __shared__ float sYg[KNB][68];     // gathered feat rows; reused for y_e at end

    // ---------------- Phase A: setup ----------------
    if (t < FC*CIN) sWp[t] = W_pos2[t];

    if (t < FC) {
        float sc = bnq_g[t] * rsqrtf(bnq_v[t] + EPS);
        float x = (feat[(long)n*FC + t] - bnq_m[t]) * sc + bnq_b[t];
        sXq[t] = x >= 0.f ? x : 0.1f * x;
    } else if (t < 128) {
        int j = t - 64;
        float sc = bn1_g[j] * rsqrtf(bn1_v[j] + EPS);
        sBn1s[j] = sc;
        sBn1b[j] = bn1_b[j] - bn1_m[j] * sc;
    } else if (t < 192) {
        int j = t - 128;
        float sc = bnr_g[j] * rsqrtf(bnr_v[j] + EPS);
        sBnrs[j] = sc;
        sBnrb[j] = bnr_b[j] - bnr_m[j] * sc;
    } else if (t < 195) {
        int i = t - 192;
        float sc = bnp_g[i] * rsqrtf(bnp_v[i] + EPS);
        float x = (s_points[(long)n*CIN + i] - bnp_m[i]) * sc + bnp_b[i];
        sPos0[i] = x >= 0.f ? x : 0.1f * x;
    } else if (t < 195 + KNB) {
        int k = t - 195;
        int idx = neighb[(long)n*KNB + k];
        sIdx[k] = idx;
        float q0 = q_points[(long)n*CIN + 0];
        float q1 = q_points[(long)n*CIN + 1];
        float q2 = q_points[(long)n*CIN + 2];
        float x0 = 0.f, x1 = 0.f, x2 = 0.f;
        if (idx < Nq) {   // idx == Nq is the shadow (zero) row
            x0 = s_points[(long)idx*CIN + 0];
            x1 = s_points[(long)idx*CIN + 1];
            x2 = s_points[(long)idx*CIN + 2];
        }
        sXv[k][0] = x0 - q0;
        sXv[k][1] = x1 - q1;
        sXv[k][2] = x2 - q2;
    }
    __syncthreads();

    // ---------------- Phase B: gather yg + attn_pre ----------------
    // 2048 (k,f) items, 8 per thread; consecutive t -> consecutive f (coalesced feat rows)
    #pragma unroll
    for (int it = 0; it < 8; ++it) {
        int e = it * 256 + t;
        int k = e >> 6, f = e & 63;
        int idx = sIdx[k];
        float yg = (idx < Nq) ? feat[(long)idx*FC + f] : 0.f;
        sYg[k][f] = yg;
        float d0 = sPos0[0] - sXv[k][0];
        float d1 = sPos0[1] - sXv[k][1];
        float d2 = sPos0[2] - sXv[k][2];
        float pos = sWp[f*3+0]*d0 + sWp[f*3+1]*d1 + sWp[f*3+2]*d2;
        // fold the 1/sqrt(Fc)=1/8 softmax scale in here
        sAttn[k][f] = (sXq[f] - yg + pos) * 0.125f;
    }
    __syncthreads();

    // ---------------- Phase C: softmax over k per f ----------------
    if (t < FC) {
        float m = -1e30f;
        #pragma unroll
        for (int k = 0; k < KNB; ++k) m = fmaxf(m, sAttn[k][t]);
        float s = 0.f;
        #pragma unroll
        for (int k = 0; k < KNB; ++k) {
            float e = __expf(sAttn[k][t] - m);
            sAttn[k][t] = e;
            s += e;
        }
        float inv = 1.f / s;
        #pragma unroll
        for (int k = 0; k < KNB; ++k) sAttn[k][t] *= inv;
    }
    __syncthreads();

    // ---------------- Phase D: attn@W_attn^T (.x_v) + yg@W_res^T + BN + lrelu ----------------
    const int k = t >> 3;       // 0..31
    const int j = t & 7;        // 0..7  -> this thread owns o = j*8 .. j*8+7
    const float xv0 = sXv[k][0], xv1 = sXv[k][1], xv2 = sXv[k][2];
    float ye[8];

    #pragma unroll
    for (int jj = 0; jj < 8; ++jj) {
        const int o = j * 8 + jj;
        const float4* __restrict__ w0 = (const float4*)(W_attn + (long)(o*3 + 0) * FC);
        const float4* __restrict__ w1 = (const float4*)(W_attn + (long)(o*3 + 1) * FC);
        const float4* __restrict__ w2 = (const float4*)(W_attn + (long)(o*3 + 2) * FC);
        float a0 = 0.f, a1 = 0.f, a2 = 0.f;
        #pragma unroll
        for (int fc = 0; fc < 16; ++fc) {
            float4 a = *(const float4*)&sAttn[k][fc*4];
            float4 u0 = w0[fc];
            float4 u1 = w1[fc];
            float4 u2 = w2[fc];
            a0 = fmaf(a.x,u0.x, fmaf(a.y,u0.y, fmaf(a.z,u0.z, fmaf(a.w,u0.w, a0))));
            a1 = fmaf(a.x,u1.x, fmaf(a.y,u1.y, fmaf(a.z,u1.z, fmaf(a.w,u1.w, a1))));
            a2 = fmaf(a.x,u2.x, fmaf(a.y,u2.y, fmaf(a.z,u2.z, fmaf(a.w,u2.w, a2))));
        }
        float y = a0*xv0 + a1*xv1 + a2*xv2;

        float r = 0.f;
        const float4* __restrict__ wr = (const float4*)(W_res + (long)o * FC);
        #pragma unroll
        for (int fc = 0; fc < 16; ++fc) {
            float4 g = *(const float4*)&sYg[k][fc*4];
            float4 u = wr[fc];
            r = fmaf(g.x,u.x, fmaf(g.y,u.y, fmaf(g.z,u.z, fmaf(g.w,u.w, r))));
        }

        float ybn = y * sBn1s[o] + sBn1b[o];
        ybn = ybn >= 0.f ? ybn : 0.1f * ybn;
        float rbn = r * sBnrs[o] + sBnrb[o];
        float v = ybn + rbn;
        ye[jj] = v >= 0.f ? v : 0.1f * v;
    }
    __syncthreads();   // everyone done READING sYg/sAttn before we overwrite

    // park y_e in sYg (reuse) for the k-max reduction
    #pragma unroll
    for (int jj = 0; jj < 8; ++jj) sYg[k][j*8 + jj] = ye[jj];
    __syncthreads();

    if (t < CO) {
        float m = -1e30f;
        #pragma unroll
        for (int kk = 0; kk < KNB; ++kk) m = fmaxf(m, sYg[kk][t]);
        out[(long)n*CO + t] = m;
    }
}

extern "C" void kernel_launch(void* const* d_in, const int* in_sizes, int n_in,
                              void* d_out, int out_size, void* d_ws, size_t ws_size,
                              hipStream_t stream) {
    const float* q_points = (const float*)d_in[0];
    const float* s_points = (const float*)d_in[1];
    const int*   neighb   = (const int*)  d_in[2];
    const float* feat     = (const float*)d_in[3];
    const float* W_pos2   = (const float*)d_in[4];
    const float* W_attn   = (const float*)d_in[5];
    const float* W_res    = (const float*)d_in[6];
    const float* bnq_g = (const float*)d_in[7];
    const float* bnq_b = (const float*)d_in[8];
    const float* bnq_m = (const float*)d_in[9];
    const float* bnq_v = (const float*)d_in[10];
    const float* bnp_g = (const float*)d_in[11];
    const float* bnp_b = (const float*)d_in[12];
    const float* bnp_m = (const float*)d_in[13];
    const float* bnp_v = (const float*)d_in[14];
    const float* bn1_g = (const float*)d_in[15];
    const float* bn1_b = (const float*)d_in[16];
    const float* bn1_m = (const float*)d_in[17];
    const float* bn1_v = (const float*)d_in[18];
    const float* bnr_g = (const float*)d_in[19];
    const float* bnr_b = (const float*)d_in[20];
    const float* bnr_m = (const float*)d_in[21];
    const float* bnr_v = (const float*)d_in[22];
    float* out = (float*)d_out;

    int Nq = in_sizes[0] / 3;   // 20000

    hipLaunchKernelGGL(GCT_61272003445298_kernel,
                       dim3(Nq), dim3(256), 0, stream,
                       q_points, s_points, neighb, feat, W_pos2, W_attn, W_res,
                       bnq_g, bnq_b, bnq_m, bnq_v,
                       bnp_g, bnp_b, bnp_m, bnp_v,
                       bn1_g, bn1_b, bn1_m, bn1_v,
                       bnr_g, bnr_b, bnr_m, bnr_v,
                       out, Nq);
}

// Round 2
// 248.322 us; speedup vs baseline: 22.8621x; 22.8621x over previous
//
#include <hip/hip_runtime.h>
#include <math.h>

// Nq=20000, K=32, Cin=3, Fc=64, Co=64. Q=2 queries per block, M=64 GEMM rows.
#define KNB 32
#define FC 64
#define CO 64
#define EPS 1e-5f

typedef __attribute__((ext_vector_type(8))) short short8;   // 8 bf16 = 4 VGPRs
typedef __attribute__((ext_vector_type(4))) float floatx4;  // MFMA C/D

__device__ __forceinline__ short f2bf(float x) {            // f32 -> bf16 RNE
    unsigned int u = __float_as_uint(x);
    u += 0x7FFFu + ((u >> 16) & 1u);
    return (short)(u >> 16);
}
__device__ __forceinline__ float bf2f(short s) {
    return __uint_as_float(((unsigned int)(unsigned short)s) << 16);
}
__device__ __forceinline__ float lrelu(float x) { return x >= 0.f ? x : 0.1f * x; }

__global__ __launch_bounds__(256) void GCT_61272003445298_kernel(
    const float* __restrict__ q_points,   // [Nq,3]
    const float* __restrict__ s_points,   // [Nq,3]
    const int*   __restrict__ neighb,     // [Nq,32]
    const float* __restrict__ feat,       // [Nq,64]
    const float* __restrict__ W_pos2,     // [64,3]
    const float* __restrict__ W_attn,     // [192,64]
    const float* __restrict__ W_res,      // [64,64]
    const float* __restrict__ bnq_g, const float* __restrict__ bnq_b,
    const float* __restrict__ bnq_m, const float* __restrict__ bnq_v,
    const float* __restrict__ bnp_g, const float* __restrict__ bnp_b,
    const float* __restrict__ bnp_m, const float* __restrict__ bnp_v,
    const float* __restrict__ bn1_g, const float* __restrict__ bn1_b,
    const float* __restrict__ bn1_m, const float* __restrict__ bn1_v,
    const float* __restrict__ bnr_g, const float* __restrict__ bnr_b,
    const float* __restrict__ bnr_m, const float* __restrict__ bnr_v,
    float* __restrict__ out, int Nq)
{
    const int n0 = blockIdx.x * 2;
    int n1 = n0 + 1;
    const bool has1 = (n1 < Nq);
    if (!has1) n1 = n0;
    const int t = threadIdx.x;

    // rows: m = q*32 + k (q in {0,1}); pitch 72 shorts = 144 B (2-way banks, free)
    __shared__ __align__(16) short sA1[64 * 72];   // attn logits -> probs, bf16
    __shared__ __align__(16) short sA2[64 * 72];   // gathered yg, bf16
    __shared__ float sXv[64][4];                   // x_v per row
    __shared__ float sXq[2][64];
    __shared__ float sPos0[2][4];
    __shared__ float sWp[192];                     // W_pos2
    __shared__ float sB1s[64], sB1b[64], sBrs[64], sBrb[64];
    __shared__ int   sIdx[64];

    // ---------------- Phase A: setup ----------------
    if (t < 192) sWp[t] = W_pos2[t];

    if (t < 64) {
        int q = t >> 5;
        long nn = q ? n1 : n0;
        int idx = neighb[nn * KNB + (t & 31)];
        sIdx[t] = idx;
        float q0 = q_points[nn * 3 + 0];
        float q1v = q_points[nn * 3 + 1];
        float q2 = q_points[nn * 3 + 2];
        float x0 = 0.f, x1 = 0.f, x2 = 0.f;
        if (idx < Nq) {                 // idx == Nq -> shadow zero row
            x0 = s_points[(long)idx * 3 + 0];
            x1 = s_points[(long)idx * 3 + 1];
            x2 = s_points[(long)idx * 3 + 2];
        }
        sXv[t][0] = x0 - q0; sXv[t][1] = x1 - q1v; sXv[t][2] = x2 - q2;
        if (t < 6) {
            int qq = t / 3, i = t % 3;
            long nn2 = qq ? n1 : n0;
            float sc = bnp_g[i] * rsqrtf(bnp_v[i] + EPS);
            sPos0[qq][i] = lrelu((s_points[nn2 * 3 + i] - bnp_m[i]) * sc + bnp_b[i]);
        }
    } else if (t < 128) {
        int j = t - 64;
        float sc = bn1_g[j] * rsqrtf(bn1_v[j] + EPS);
        sB1s[j] = sc; sB1b[j] = bn1_b[j] - bn1_m[j] * sc;
    } else if (t < 192) {
        int j = t - 128;
        float sc = bnr_g[j] * rsqrtf(bnr_v[j] + EPS);
        sBrs[j] = sc; sBrb[j] = bnr_b[j] - bnr_m[j] * sc;
    } else {
        int f = t - 192;
        float sc = bnq_g[f] * rsqrtf(bnq_v[f] + EPS);
        float mm = bnq_m[f], bb = bnq_b[f];
        sXq[0][f] = lrelu((feat[(long)n0 * FC + f] - mm) * sc + bb);
        sXq[1][f] = lrelu((feat[(long)n1 * FC + f] - mm) * sc + bb);
    }
    __syncthreads();

    // ---------------- Phase B: gather yg + logits (bf16, pre-scaled by 1/8) ----
    // 64 rows x 16 float4 = 1024 items, 4 per thread; 16 consecutive threads = 1 row
    #pragma unroll
    for (int it = 0; it < 4; ++it) {
        int e = it * 256 + t;
        int row = e >> 4, fq = e & 15;
        int q = row >> 5;
        int idx = sIdx[row];
        float4 y;
        if (idx < Nq) y = *(const float4*)(feat + (long)idx * FC + fq * 4);
        else          y = make_float4(0.f, 0.f, 0.f, 0.f);
        *(short4*)(sA2 + row * 72 + fq * 4) =
            make_short4(f2bf(y.x), f2bf(y.y), f2bf(y.z), f2bf(y.w));
        float d0 = sPos0[q][0] - sXv[row][0];
        float d1 = sPos0[q][1] - sXv[row][1];
        float d2 = sPos0[q][2] - sXv[row][2];
        float4 xq4 = *(const float4*)&sXq[q][fq * 4];
        float yv[4]  = {y.x, y.y, y.z, y.w};
        float xqv[4] = {xq4.x, xq4.y, xq4.z, xq4.w};
        short lb[4];
        #pragma unroll
        for (int c = 0; c < 4; ++c) {
            int f = fq * 4 + c;
            float pos = sWp[f * 3 + 0] * d0 + sWp[f * 3 + 1] * d1 + sWp[f * 3 + 2] * d2;
            lb[c] = f2bf((xqv[c] - yv[c] + pos) * 0.125f);
        }
        *(short4*)(sA1 + row * 72 + fq * 4) = make_short4(lb[0], lb[1], lb[2], lb[3]);
    }
    __syncthreads();

    // ---------------- Phase C: softmax over k (32 rows per query) --------------
    {
        int col = t >> 1, h = t & 1;          // 128 cols x 2 halves
        int q = col >> 6, f = col & 63;
        short* p = sA1 + (q * 32 + h * 16) * 72 + f;
        float m = -1e30f;
        #pragma unroll
        for (int j = 0; j < 16; ++j) m = fmaxf(m, bf2f(p[j * 72]));
        m = fmaxf(m, __shfl_xor(m, 1));
        float s = 0.f;
        #pragma unroll
        for (int j = 0; j < 16; ++j) {
            float e = __expf(bf2f(p[j * 72]) - m);
            s += e;
            p[j * 72] = f2bf(e);
        }
        s += __shfl_xor(s, 1);
        float inv = 1.f / s;
        #pragma unroll
        for (int j = 0; j < 16; ++j) p[j * 72] = f2bf(bf2f(p[j * 72]) * inv);
    }
    __syncthreads();

    // ---------------- Phase D: MFMA GEMMs ----------------
    // wave wv owns output cols o = wv*16 .. +15.
    // B rows: type i<3 -> W_attn[o*3+i]; type 3 -> W_res[o]. Same-lane i-partials.
    const int wv = t >> 6;
    const int lane = t & 63;
    const int c = lane & 15, quad = lane >> 4;
    const int o = wv * 16 + c;

    short8 bW[4][2];
    #pragma unroll
    for (int ty = 0; ty < 4; ++ty) {
        const float* wrow = (ty < 3) ? (W_attn + (long)(o * 3 + ty) * FC)
                                     : (W_res  + (long)o * FC);
        #pragma unroll
        for (int ks = 0; ks < 2; ++ks) {
            int k0 = ks * 32 + quad * 8;
            float4 w0 = *(const float4*)(wrow + k0);
            float4 w1 = *(const float4*)(wrow + k0 + 4);
            short8 b;
            b[0] = f2bf(w0.x); b[1] = f2bf(w0.y); b[2] = f2bf(w0.z); b[3] = f2bf(w0.w);
            b[4] = f2bf(w1.x); b[5] = f2bf(w1.y); b[6] = f2bf(w1.z); b[7] = f2bf(w1.w);
            bW[ty][ks] = b;
        }
    }

    floatx4 acc[4][4];
    #pragma unroll
    for (int mt = 0; mt < 4; ++mt)
        #pragma unroll
        for (int ty = 0; ty < 4; ++ty)
            acc[mt][ty] = (floatx4){0.f, 0.f, 0.f, 0.f};

    #pragma unroll
    for (int mt = 0; mt < 4; ++mt) {
        int r = mt * 16 + c;                       // A row m = lane&15
        #pragma unroll
        for (int ks = 0; ks < 2; ++ks) {
            int kof = ks * 32 + quad * 8;          // A k-slice = quad*8+j
            short8 a1 = *(const short8*)(sA1 + r * 72 + kof);
            short8 a2 = *(const short8*)(sA2 + r * 72 + kof);
            acc[mt][0] = __builtin_amdgcn_mfma_f32_16x16x32_bf16(a1, bW[0][ks], acc[mt][0], 0, 0, 0);
            acc[mt][1] = __builtin_amdgcn_mfma_f32_16x16x32_bf16(a1, bW[1][ks], acc[mt][1], 0, 0, 0);
            acc[mt][2] = __builtin_amdgcn_mfma_f32_16x16x32_bf16(a1, bW[2][ks], acc[mt][2], 0, 0, 0);
            acc[mt][3] = __builtin_amdgcn_mfma_f32_16x16x32_bf16(a2, bW[3][ks], acc[mt][3], 0, 0, 0);
        }
    }

    // ---------------- Epilogue: xv-contract, BN, lrelu, k-max ----------------
    // C/D: col = lane&15 (=c), row = quad*4 + reg  [measured m89]
    float s1 = sB1s[o], b1 = sB1b[o], sr = sBrs[o], br = sBrb[o];
    float m0 = -1e30f, m1 = -1e30f;
    #pragma unroll
    for (int mt = 0; mt < 4; ++mt) {
        #pragma unroll
        for (int reg = 0; reg < 4; ++reg) {
            int r = mt * 16 + quad * 4 + reg;
            float y = acc[mt][0][reg] * sXv[r][0]
                    + acc[mt][1][reg] * sXv[r][1]
                    + acc[mt][2][reg] * sXv[r][2];
            float ybn = lrelu(y * s1 + b1);
            float rbn = acc[mt][3][reg] * sr + br;
            float v = lrelu(ybn + rbn);
            if (mt < 2) m0 = fmaxf(m0, v); else m1 = fmaxf(m1, v);
        }
    }
    m0 = fmaxf(m0, __shfl_xor(m0, 16));
    m0 = fmaxf(m0, __shfl_xor(m0, 32));
    m1 = fmaxf(m1, __shfl_xor(m1, 16));
    m1 = fmaxf(m1, __shfl_xor(m1, 32));
    if (lane < 16) {
        out[(long)n0 * CO + o] = m0;
        if (has1) out[(long)n1 * CO + o] = m1;
    }
}

extern "C" void kernel_launch(void* const* d_in, const int* in_sizes, int n_in,
                              void* d_out, int out_size, void* d_ws, size_t ws_size,
                              hipStream_t stream) {
    const float* q_points = (const float*)d_in[0];
    const float* s_points = (const float*)d_in[1];
    const int*   neighb   = (const int*)  d_in[2];
    const float* feat     = (const float*)d_in[3];
    const float* W_pos2   = (const float*)d_in[4];
    const float* W_attn   = (const float*)d_in[5];
    const float* W_res    = (const float*)d_in[6];
    const float* bnq_g = (const float*)d_in[7];
    const float* bnq_b = (const float*)d_in[8];
    const float* bnq_m = (const float*)d_in[9];
    const float* bnq_v = (const float*)d_in[10];
    const float* bnp_g = (const float*)d_in[11];
    const float* bnp_b = (const float*)d_in[12];
    const float* bnp_m = (const float*)d_in[13];
    const float* bnp_v = (const float*)d_in[14];
    const float* bn1_g = (const float*)d_in[15];
    const float* bn1_b = (const float*)d_in[16];
    const float* bn1_m = (const float*)d_in[17];
    const float* bn1_v = (const float*)d_in[18];
    const float* bnr_g = (const float*)d_in[19];
    const float* bnr_b = (const float*)d_in[20];
    const float* bnr_m = (const float*)d_in[21];
    const float* bnr_v = (const float*)d_in[22];
    float* out = (float*)d_out;

    int Nq = in_sizes[0] / 3;               // 20000
    int nb = (Nq + 1) / 2;                  // 2 queries per block

    hipLaunchKernelGGL(GCT_61272003445298_kernel,
                       dim3(nb), dim3(256), 0, stream,
                       q_points, s_points, neighb, feat, W_pos2, W_attn, W_res,
                       bnq_g, bnq_b, bnq_m, bnq_v,
                       bnp_g, bnp_b, bnp_m, bnp_v,
                       bn1_g, bn1_b, bn1_m, bn1_v,
                       bnr_g, bnr_b, bnr_m, bnr_v,
                       out, Nq);
}

// Round 3
// 173.154 us; speedup vs baseline: 32.7869x; 1.4341x over previous
//
#include <hip/hip_runtime.h>
#include <math.h>

// Nq=20000, K=32, Cin=3, Fc=64, Co=64. Persistent blocks; 2 queries (64 rows) per iter.
#define KNB 32
#define FC 64
#define CO 64
#define EPS 1e-5f
#define NBLOCKS 1024

typedef __attribute__((ext_vector_type(8))) short short8;   // 8 bf16 = 4 VGPRs
typedef __attribute__((ext_vector_type(4))) float floatx4;  // MFMA C/D

__device__ __forceinline__ short f2bf(float x) {            // f32 -> bf16 RNE
    unsigned int u = __float_as_uint(x);
    u += 0x7FFFu + ((u >> 16) & 1u);
    return (short)(u >> 16);
}
__device__ __forceinline__ float bf2f(short s) {
    return __uint_as_float(((unsigned int)(unsigned short)s) << 16);
}
__device__ __forceinline__ float lrelu(float x) { return fmaxf(x, 0.1f * x); }

__global__ __launch_bounds__(256, 4) void GCT_61272003445298_kernel(
    const float* __restrict__ q_points,   // [Nq,3]
    const float* __restrict__ s_points,   // [Nq,3]
    const int*   __restrict__ neighb,     // [Nq,32]
    const float* __restrict__ feat,       // [Nq,64]
    const float* __restrict__ W_pos2,     // [64,3]
    const float* __restrict__ W_attn,     // [192,64]
    const float* __restrict__ W_res,      // [64,64]
    const float* __restrict__ bnq_g, const float* __restrict__ bnq_b,
    const float* __restrict__ bnq_m, const float* __restrict__ bnq_v,
    const float* __restrict__ bnp_g, const float* __restrict__ bnp_b,
    const float* __restrict__ bnp_m, const float* __restrict__ bnp_v,
    const float* __restrict__ bn1_g, const float* __restrict__ bn1_b,
    const float* __restrict__ bn1_m, const float* __restrict__ bn1_v,
    const float* __restrict__ bnr_g, const float* __restrict__ bnr_b,
    const float* __restrict__ bnr_m, const float* __restrict__ bnr_v,
    float* __restrict__ out, int Nq)
{
    const int t = threadIdx.x;
    const int wv = t >> 6;
    const int lane = t & 63;
    const int cc = lane & 15, quad = lane >> 4;
    const int o = wv * 16 + cc;            // this lane's output channel

    // rows: m = q*32 + k; pitch 72 shorts = 144 B (2-way bank aliasing = free)
    __shared__ __align__(16) short sA1[64 * 72];   // logits -> probs, bf16
    __shared__ __align__(16) short sA2[64 * 72];   // gathered yg, bf16
    __shared__ float sXv[64][4];                   // x_v per row
    __shared__ float sXq[2][64];
    __shared__ float sPos0[2][4];
    __shared__ float sWp[192];
    __shared__ float sQs[64], sQb[64];             // bnq folded scale/bias
    __shared__ float sPs[4], sPb[4];               // bnp folded
    __shared__ int   sIdx[64];

    // ---------------- one-time setup ----------------
    if (t < 192) sWp[t] = W_pos2[t];
    if (t < 64) {
        float sc = bnq_g[t] * rsqrtf(bnq_v[t] + EPS);
        sQs[t] = sc; sQb[t] = bnq_b[t] - bnq_m[t] * sc;
        if (t < 3) {
            float scp = bnp_g[t] * rsqrtf(bnp_v[t] + EPS);
            sPs[t] = scp; sPb[t] = bnp_b[t] - bnp_m[t] * scp;
        }
    }
    // per-lane epilogue BN params (o fixed per lane)
    const float e1s = bn1_g[o] * rsqrtf(bn1_v[o] + EPS);
    const float e1b = bn1_b[o] - bn1_m[o] * e1s;
    const float ers = bnr_g[o] * rsqrtf(bnr_v[o] + EPS);
    const float erb = bnr_b[o] - bnr_m[o] * ers;

    // persistent bf16 weight fragments: type 0..2 -> W_attn[o*3+ty], 3 -> W_res[o]
    short8 bW[4][2];
    #pragma unroll
    for (int ty = 0; ty < 4; ++ty) {
        const float* wrow = (ty < 3) ? (W_attn + (long)(o * 3 + ty) * FC)
                                     : (W_res  + (long)o * FC);
        #pragma unroll
        for (int ks = 0; ks < 2; ++ks) {
            int k0 = ks * 32 + quad * 8;
            float4 w0 = *(const float4*)(wrow + k0);
            float4 w1 = *(const float4*)(wrow + k0 + 4);
            short8 b;
            b[0] = f2bf(w0.x); b[1] = f2bf(w0.y); b[2] = f2bf(w0.z); b[3] = f2bf(w0.w);
            b[4] = f2bf(w1.x); b[5] = f2bf(w1.y); b[6] = f2bf(w1.z); b[7] = f2bf(w1.w);
            bW[ty][ks] = b;
        }
    }
    __syncthreads();

    const int npair = (Nq + 1) >> 1;
    for (int p = blockIdx.x; p < npair; p += NBLOCKS) {
        const long n0 = 2L * p;
        long n1 = n0 + 1;
        const bool has1 = (n1 < Nq);
        if (!has1) n1 = n0;

        // ---------------- Phase A: per-pair setup ----------------
        if (t < 64) {
            int q = t >> 5;
            long nn = q ? n1 : n0;
            int idx = neighb[nn * KNB + (t & 31)];
            sIdx[t] = idx;
            float q0 = q_points[nn * 3 + 0];
            float q1v = q_points[nn * 3 + 1];
            float q2 = q_points[nn * 3 + 2];
            float x0 = 0.f, x1 = 0.f, x2 = 0.f;
            if (idx < Nq) {                 // idx == Nq -> shadow zero row
                x0 = s_points[(long)idx * 3 + 0];
                x1 = s_points[(long)idx * 3 + 1];
                x2 = s_points[(long)idx * 3 + 2];
            }
            sXv[t][0] = x0 - q0; sXv[t][1] = x1 - q1v; sXv[t][2] = x2 - q2;
            if (t < 6) {
                int qq = t / 3, i = t % 3;
                long nn2 = qq ? n1 : n0;
                sPos0[qq][i] = lrelu(s_points[nn2 * 3 + i] * sPs[i] + sPb[i]);
            }
        } else if (t >= 192) {
            int f = t - 192;
            float sc = sQs[f], bb = sQb[f];
            sXq[0][f] = lrelu(feat[n0 * FC + f] * sc + bb);
            sXq[1][f] = lrelu(feat[n1 * FC + f] * sc + bb);
        }
        __syncthreads();

        // ---------------- Phase B: gather yg + logits (bf16, pre-scaled 1/8) ---
        // 64 rows x 16 float4; fq = t&15 fixed per thread -> Wp/xq reads hoisted
        #pragma unroll
        for (int it = 0; it < 4; ++it) {
            int e = it * 256 + t;
            int row = e >> 4, fq = e & 15;
            int q = row >> 5;
            int idx = sIdx[row];
            float4 y;
            if (idx < Nq) y = *(const float4*)(feat + (long)idx * FC + fq * 4);
            else          y = make_float4(0.f, 0.f, 0.f, 0.f);
            *(short4*)(sA2 + row * 72 + fq * 4) =
                make_short4(f2bf(y.x), f2bf(y.y), f2bf(y.z), f2bf(y.w));
            float d0 = sPos0[q][0] - sXv[row][0];
            float d1 = sPos0[q][1] - sXv[row][1];
            float d2 = sPos0[q][2] - sXv[row][2];
            float4 xq4 = *(const float4*)&sXq[q][fq * 4];
            float yv[4]  = {y.x, y.y, y.z, y.w};
            float xqv[4] = {xq4.x, xq4.y, xq4.z, xq4.w};
            short lb[4];
            #pragma unroll
            for (int c = 0; c < 4; ++c) {
                int f = fq * 4 + c;
                float pos = sWp[f * 3 + 0] * d0 + sWp[f * 3 + 1] * d1 + sWp[f * 3 + 2] * d2;
                lb[c] = f2bf((xqv[c] - yv[c] + pos) * 0.125f);
            }
            *(short4*)(sA1 + row * 72 + fq * 4) = make_short4(lb[0], lb[1], lb[2], lb[3]);
        }
        __syncthreads();

        // ---------------- Phase C: softmax over k, single LDS round-trip -------
        {
            int col = t >> 1, h = t & 1;          // 128 cols x 2 k-halves
            int q = col >> 6, f = col & 63;
            short* pp = sA1 + (q * 32 + h * 16) * 72 + f;
            float l[16];
            float m = -1e30f;
            #pragma unroll
            for (int j = 0; j < 16; ++j) { l[j] = bf2f(pp[j * 72]); m = fmaxf(m, l[j]); }
            m = fmaxf(m, __shfl_xor(m, 1));
            float s = 0.f;
            #pragma unroll
            for (int j = 0; j < 16; ++j) { float e = __expf(l[j] - m); s += e; l[j] = e; }
            s += __shfl_xor(s, 1);
            float inv = 1.f / s;
            #pragma unroll
            for (int j = 0; j < 16; ++j) pp[j * 72] = f2bf(l[j] * inv);
        }
        __syncthreads();

        // ---------------- Phase D: MFMA + fused epilogue per 16-row tile -------
        float m0 = -1e30f, m1 = -1e30f;
        #pragma unroll
        for (int mt = 0; mt < 4; ++mt) {
            floatx4 acc[4];
            #pragma unroll
            for (int ty = 0; ty < 4; ++ty) acc[ty] = (floatx4){0.f, 0.f, 0.f, 0.f};
            int r0 = mt * 16 + cc;                 // A row m = lane&15
            #pragma unroll
            for (int ks = 0; ks < 2; ++ks) {
                int kof = ks * 32 + quad * 8;      // A k-slice = quad*8+j
                short8 a1 = *(const short8*)(sA1 + r0 * 72 + kof);
                short8 a2 = *(const short8*)(sA2 + r0 * 72 + kof);
                acc[0] = __builtin_amdgcn_mfma_f32_16x16x32_bf16(a1, bW[0][ks], acc[0], 0, 0, 0);
                acc[1] = __builtin_amdgcn_mfma_f32_16x16x32_bf16(a1, bW[1][ks], acc[1], 0, 0, 0);
                acc[2] = __builtin_amdgcn_mfma_f32_16x16x32_bf16(a1, bW[2][ks], acc[2], 0, 0, 0);
                acc[3] = __builtin_amdgcn_mfma_f32_16x16x32_bf16(a2, bW[3][ks], acc[3], 0, 0, 0);
            }
            // C/D: col = lane&15, row = quad*4 + reg
            #pragma unroll
            for (int reg = 0; reg < 4; ++reg) {
                int r = mt * 16 + quad * 4 + reg;
                float4 xv = *(const float4*)&sXv[r][0];
                float y = acc[0][reg] * xv.x + acc[1][reg] * xv.y + acc[2][reg] * xv.z;
                float ybn = lrelu(y * e1s + e1b);
                float rbn = acc[3][reg] * ers + erb;
                float v = lrelu(ybn + rbn);
                if (mt < 2) m0 = fmaxf(m0, v); else m1 = fmaxf(m1, v);
            }
        }
        m0 = fmaxf(m0, __shfl_xor(m0, 16));
        m0 = fmaxf(m0, __shfl_xor(m0, 32));
        m1 = fmaxf(m1, __shfl_xor(m1, 16));
        m1 = fmaxf(m1, __shfl_xor(m1, 32));
        if (lane < 16) {
            out[n0 * CO + o] = m0;
            if (has1) out[n1 * CO + o] = m1;
        }
        __syncthreads();   // protect sA1/sA2/sXv/sXq before next iteration
    }
}

extern "C" void kernel_launch(void* const* d_in, const int* in_sizes, int n_in,
                              void* d_out, int out_size, void* d_ws, size_t ws_size,
                              hipStream_t stream) {
    const float* q_points = (const float*)d_in[0];
    const float* s_points = (const float*)d_in[1];
    const int*   neighb   = (const int*)  d_in[2];
    const float* feat     = (const float*)d_in[3];
    const float* W_pos2   = (const float*)d_in[4];
    const float* W_attn   = (const float*)d_in[5];
    const float* W_res    = (const float*)d_in[6];
    const float* bnq_g = (const float*)d_in[7];
    const float* bnq_b = (const float*)d_in[8];
    const float* bnq_m = (const float*)d_in[9];
    const float* bnq_v = (const float*)d_in[10];
    const float* bnp_g = (const float*)d_in[11];
    const float* bnp_b = (const float*)d_in[12];
    const float* bnp_m = (const float*)d_in[13];
    const float* bnp_v = (const float*)d_in[14];
    const float* bn1_g = (const float*)d_in[15];
    const float* bn1_b = (const float*)d_in[16];
    const float* bn1_m = (const float*)d_in[17];
    const float* bn1_v = (const float*)d_in[18];
    const float* bnr_g = (const float*)d_in[19];
    const float* bnr_b = (const float*)d_in[20];
    const float* bnr_m = (const float*)d_in[21];
    const float* bnr_v = (const float*)d_in[22];
    float* out = (float*)d_out;

    int Nq = in_sizes[0] / 3;               // 20000

    hipLaunchKernelGGL(GCT_61272003445298_kernel,
                       dim3(NBLOCKS), dim3(256), 0, stream,
                       q_points, s_points, neighb, feat, W_pos2, W_attn, W_res,
                       bnq_g, bnq_b, bnq_m, bnq_v,
                       bnp_g, bnp_b, bnp_m, bnp_v,
                       bn1_g, bn1_b, bn1_m, bn1_v,
                       bnr_g, bnr_b, bnr_m, bnr_v,
                       out, Nq);
}